// Round 9
// baseline (242.241 us; speedup 1.0000x reference)
//
#include <hip/hip_runtime.h>
#include <hip/hip_fp16.h>

#define F_DIM 128
#define H_DIM 16
#define NPB 128          // nodes per bucket (power of 2, dst>>7)
#define NPB_SHIFT 7
#define NB_MAX 1024      // max buckets supported (n <= 131072)
#define NBLK1 256        // blocks in bucketing passes
#define T1 1024          // threads in bucketing passes

struct __align__(8) h4 { __half2 a, b; };  // 4 halves, one dwordx2

// ---- phase 1a: per-block per-bucket edge counts -> cnt_mat[block][bucket] ----
__global__ __launch_bounds__(1024) void k_count(const int* __restrict__ dst, int e,
                                                int* __restrict__ cnt_mat, int nb) {
    __shared__ int hist[NB_MAX];
    for (int b = threadIdx.x; b < nb; b += T1) hist[b] = 0;
    __syncthreads();
    int chunk = (e + NBLK1 - 1) / NBLK1;
    int lo = blockIdx.x * chunk;
    int hi = min(e, lo + chunk);
    for (int i = lo + threadIdx.x; i < hi; i += T1)
        atomicAdd(&hist[__builtin_nontemporal_load(dst + i) >> NPB_SHIFT], 1);
    __syncthreads();
    for (int b = threadIdx.x; b < nb; b += T1)
        cnt_mat[(size_t)blockIdx.x * nb + b] = hist[b];  // coalesced row write
}

// ---- phase 1b-1: bucket totals tot[b] = sum over blocks (column sums) ----
__global__ void k_rowsum(const int* __restrict__ cnt_mat, int* __restrict__ tot, int nb) {
    int b = blockIdx.x, t = threadIdx.x;  // 64 threads
    int s = 0;
    for (int k = t; k < NBLK1; k += 64) s += cnt_mat[(size_t)k * nb + b];
#pragma unroll
    for (int off = 32; off > 0; off >>= 1) s += __shfl_down(s, off);
    if (t == 0) tot[b] = s;
}

// ---- phase 1b-2: exclusive scan of bucket totals -> starts (col offsets) ----
__global__ void k_scan2(const int* __restrict__ tot, int* __restrict__ starts, int nb) {
    __shared__ int s[1024];
    int t = threadIdx.x;
    s[t] = (t < nb) ? tot[t] : 0;
    __syncthreads();
    for (int off = 1; off < 1024; off <<= 1) {
        int u = (t >= off) ? s[t - off] : 0;
        __syncthreads();
        s[t] += u;
        __syncthreads();
    }
    if (t == 0) starts[0] = 0;
    if (t < nb) starts[t + 1] = s[t];
}

// ---- phase 1c: per-BLOCK exclusive scan over buckets -> blk_base[block][bucket] ----
// Block blk's region in packed is [blk*chunk, blk*chunk + its edge count): contiguous.
__global__ __launch_bounds__(1024) void k_bases2(const int* __restrict__ cnt_mat,
                                                 int* __restrict__ blk_base, int e, int nb) {
    __shared__ int s[NB_MAX];
    int blk = blockIdx.x, t = threadIdx.x;
    int chunk = (e + NBLK1 - 1) / NBLK1;
    int v = (t < nb) ? cnt_mat[(size_t)blk * nb + t] : 0;
    s[t] = v;
    __syncthreads();
    for (int off = 1; off < NB_MAX; off <<= 1) {
        int u = (t >= off) ? s[t - off] : 0;
        __syncthreads();
        s[t] += u;
        __syncthreads();
    }
    if (t < nb) blk_base[(size_t)blk * nb + t] = blk * chunk + s[t] - v;
}

// ---- phase 1d: tile-sorted placement into block-CONTIGUOUS region ----
// packed layout: [block][bucket]. Each block writes only its own 50 KB region:
// no cross-block line sharing, dirty lines stay in the block's XCD L2.
__global__ __launch_bounds__(1024) void k_place(
        const int* __restrict__ src, const int* __restrict__ dst, int e,
        const int* __restrict__ blk_base, int* __restrict__ packed, int nb) {
    __shared__ int tcnt[NB_MAX];
    __shared__ int toff[NB_MAX];   // exclusive offsets within tile
    __shared__ int gcur[NB_MAX];   // running cursor within block's per-bucket run
    __shared__ int stage[T1];
    __shared__ short sbkt[T1];
    __shared__ int wsum[16];
    __shared__ int wpre[16];
    int t = threadIdx.x;
    int lane = t & 63, wv = t >> 6;
    const int* mybase = blk_base + (size_t)blockIdx.x * nb;
    for (int b = t; b < nb; b += T1) gcur[b] = 0;
    int chunk = (e + NBLK1 - 1) / NBLK1;
    int lo = blockIdx.x * chunk;
    int hi = min(e, lo + chunk);

    for (int tile = lo; tile < hi; tile += T1) {
        for (int b = t; b < nb; b += T1) tcnt[b] = 0;
        __syncthreads();
        // classify (nontemporal streaming reads: don't evict staging lines)
        int i = tile + t;
        int b = -1, val = 0, r = 0;
        if (i < hi) {
            int d = __builtin_nontemporal_load(dst + i);
            int sv = __builtin_nontemporal_load(src + i);
            b = d >> NPB_SHIFT;
            val = sv | ((d & (NPB - 1)) << 17);
            r = atomicAdd(&tcnt[b], 1);
        }
        __syncthreads();
        // exclusive scan of tcnt[0..1023]: wave shfl-scan + 16-partial scan
        int v = tcnt[t];
        int sc = v;
#pragma unroll
        for (int off = 1; off < 64; off <<= 1) {
            int u = __shfl_up(sc, off);
            if (lane >= off) sc += u;
        }
        if (lane == 63) wsum[wv] = sc;
        __syncthreads();
        if (t < 16) {
            int s = wsum[t];
#pragma unroll
            for (int off = 1; off < 16; off <<= 1) {
                int u = __shfl_up(s, off);
                if (lane >= off) s += u;
            }
            wpre[t] = s;
        }
        __syncthreads();
        toff[t] = sc - v + (wv ? wpre[wv - 1] : 0);
        __syncthreads();
        // stage sorted by bucket
        if (b >= 0) {
            int slot = toff[b] + r;
            stage[slot] = val;
            sbkt[slot] = (short)b;
        }
        __syncthreads();
        // coalesced write into this block's own contiguous region
        int tilecnt = min(hi - tile, T1);
        if (t < tilecnt) {
            int bb = sbkt[t];
            int pos = mybase[bb] + gcur[bb] + (t - toff[bb]);
            packed[pos] = stage[t];
        }
        __syncthreads();
        for (int bb = t; bb < nb; bb += T1) gcur[bb] += tcnt[bb];
        __syncthreads();
    }
}

// ---- phase 2: per-bucket counting sort -> CSR (col, rowp, rowe) + dis ----
// Bucket b's edges live in 256 runs: (blk_base[blk][b], cnt_mat[blk][b]).
__global__ __launch_bounds__(256) void k_sort(
        const int* __restrict__ packed, const int* __restrict__ cnt_mat,
        const int* __restrict__ blk_base, const int* __restrict__ starts,
        int* __restrict__ col, int* __restrict__ rowp, int* __restrict__ rowe,
        float* __restrict__ dis, int n, int nb) {
    __shared__ int cnt[NPB];
    __shared__ int scan_s[NPB];
    __shared__ int base_s[NPB];
    __shared__ int runb[NBLK1];
    __shared__ int runc[NBLK1];
    int b = blockIdx.x, t = threadIdx.x;
    if (t < NPB) cnt[t] = 0;
    runb[t] = blk_base[(size_t)t * nb + b];   // t = 0..255 = run index
    runc[t] = cnt_mat[(size_t)t * nb + b];
    __syncthreads();
    // histogram by dst_local: each thread walks its run (sequential reads)
    {
        int base = runb[t], c = runc[t];
        for (int k = 0; k < c; k++)
            atomicAdd(&cnt[packed[base + k] >> 17], 1);
    }
    __syncthreads();
    if (t < NPB) scan_s[t] = cnt[t];
    __syncthreads();
    for (int off = 1; off < NPB; off <<= 1) {
        int v = 0;
        if (t < NPB && t >= off) v = scan_s[t - off];
        __syncthreads();
        if (t < NPB) scan_s[t] += v;
        __syncthreads();
    }
    int i0 = b * NPB;
    if (t < NPB) {
        int c = cnt[t];
        base_s[t] = starts[b] + scan_s[t] - c;
        int i = i0 + t;
        if (i < n) {
            rowp[i] = base_s[t];
            rowe[i] = base_s[t] + c;
            dis[i] = rsqrtf(1.0f + (float)c);  // +1 self-loop
        }
        cnt[t] = 0;  // reuse as cursor
    }
    __syncthreads();
    {
        int base = runb[t], c = runc[t];
        for (int k = 0; k < c; k++) {
            int w = packed[base + k];
            int dl = w >> 17;
            int pos = base_s[dl] + atomicAdd(&cnt[dl], 1);
            col[pos] = w & 0x1FFFF;
        }
    }
}

// ---- g = dis_i*(x_i@W1), stored fp16 ----
__global__ void k_gemm1(const float* __restrict__ x, const float* __restrict__ W1,
                        const float* __restrict__ dis, __half* __restrict__ gh, int n) {
    __shared__ float Ws[F_DIM * H_DIM];
    for (int t = threadIdx.x; t < F_DIM * H_DIM; t += blockDim.x) Ws[t] = W1[t];
    __syncthreads();
    int i = blockIdx.x * blockDim.x + threadIdx.x;
    if (i >= n) return;

    float acc[H_DIM];
#pragma unroll
    for (int j = 0; j < H_DIM; j++) acc[j] = 0.0f;

    const float4* xv = (const float4*)(x + (size_t)i * F_DIM);
#pragma unroll 4
    for (int k4 = 0; k4 < F_DIM / 4; k4++) {
        float4 v = xv[k4];
        int k = k4 * 4;
#pragma unroll
        for (int j = 0; j < H_DIM; j++) acc[j] += v.x * Ws[(k + 0) * H_DIM + j];
#pragma unroll
        for (int j = 0; j < H_DIM; j++) acc[j] += v.y * Ws[(k + 1) * H_DIM + j];
#pragma unroll
        for (int j = 0; j < H_DIM; j++) acc[j] += v.z * Ws[(k + 2) * H_DIM + j];
#pragma unroll
        for (int j = 0; j < H_DIM; j++) acc[j] += v.w * Ws[(k + 3) * H_DIM + j];
    }
    float d = dis[i];
    __half2* hp = (__half2*)(gh + ((size_t)i << 4));
#pragma unroll
    for (int p = 0; p < 8; p++)
        hp[p] = __floats2half2_rn(d * acc[2 * p], d * acc[2 * p + 1]);
}

// ---- conv1 per-node register aggregation + relu + W2 -> g2 ----
__global__ __launch_bounds__(256) void k_p2n(
        const int* __restrict__ col, const int* __restrict__ rowp,
        const int* __restrict__ rowe, const __half* __restrict__ gh,
        const float* __restrict__ dis, const float* __restrict__ b1,
        const float* __restrict__ W2, float* __restrict__ g2, int n) {
    int t = threadIdx.x;
    int i = blockIdx.x * 64 + (t >> 2);
    int c = t & 3;
    if (i >= n) return;
    int lo = rowp[i], hi = rowe[i];

    h4 us = *(const h4*)(gh + ((size_t)i << 4) + (c << 2));
    float2 s0 = __half22float2(us.a), s1 = __half22float2(us.b);
    float a0 = s0.x, a1 = s0.y, a2 = s1.x, a3 = s1.y;

    for (int base = lo; base < hi; base += 8) {
        int last = hi - 1;
        int idx[8]; h4 u[8]; float m[8];
#pragma unroll
        for (int k = 0; k < 8; k++) {
            int e = base + k;
            bool v = e < hi;
            idx[k] = col[v ? e : last];
            m[k] = v ? 1.0f : 0.0f;
        }
#pragma unroll
        for (int k = 0; k < 8; k++)
            u[k] = *(const h4*)(gh + ((size_t)idx[k] << 4) + (c << 2));
#pragma unroll
        for (int k = 0; k < 8; k++) {
            float2 f0 = __half22float2(u[k].a);
            float2 f1 = __half22float2(u[k].b);
            a0 += f0.x * m[k]; a1 += f0.y * m[k];
            a2 += f1.x * m[k]; a3 += f1.y * m[k];
        }
    }

    float d = dis[i];
    int j0 = c << 2;
    float p = 0.0f;
    p += fmaxf(fmaf(d, a0, b1[j0 + 0]), 0.0f) * W2[j0 + 0];
    p += fmaxf(fmaf(d, a1, b1[j0 + 1]), 0.0f) * W2[j0 + 1];
    p += fmaxf(fmaf(d, a2, b1[j0 + 2]), 0.0f) * W2[j0 + 2];
    p += fmaxf(fmaf(d, a3, b1[j0 + 3]), 0.0f) * W2[j0 + 3];
    p += __shfl_xor(p, 1);
    p += __shfl_xor(p, 2);
    if (c == 0) g2[i] = d * p;
}

// ---- conv2 per-node register aggregation -> out ----
__global__ __launch_bounds__(256) void k_p3n(
        const int* __restrict__ col, const int* __restrict__ rowp,
        const int* __restrict__ rowe, const float* __restrict__ g2,
        const float* __restrict__ dis, const float* __restrict__ b2,
        float* __restrict__ out, int n) {
    int i = blockIdx.x * 256 + threadIdx.x;
    if (i >= n) return;
    int lo = rowp[i], hi = rowe[i];
    float s = g2[i];
    for (int base = lo; base < hi; base += 8) {
        int idx[8]; float v[8]; bool ok[8];
        int last = hi - 1;
#pragma unroll
        for (int k = 0; k < 8; k++) {
            int e = base + k;
            ok[k] = e < hi;
            idx[k] = col[ok[k] ? e : last];
        }
#pragma unroll
        for (int k = 0; k < 8; k++) v[k] = g2[idx[k]];
#pragma unroll
        for (int k = 0; k < 8; k++) s += ok[k] ? v[k] : 0.0f;
    }
    out[i] = b2[0] + dis[i] * s;
}

extern "C" void kernel_launch(void* const* d_in, const int* in_sizes, int n_in,
                              void* d_out, int out_size, void* d_ws, size_t ws_size,
                              hipStream_t stream) {
    const float* x  = (const float*)d_in[0];
    const int*   ei = (const int*)d_in[1];
    const float* W1 = (const float*)d_in[2];
    const float* b1 = (const float*)d_in[3];
    const float* W2 = (const float*)d_in[4];
    const float* b2 = (const float*)d_in[5];

    const int n = in_sizes[0] / F_DIM;
    const int e = in_sizes[1] / 2;
    const int* src = ei;
    const int* dst = ei + e;
    const int nb = (n + NPB - 1) / NPB;

    // workspace layout, regions rounded to 256 B
    char* p = (char*)d_ws;
    auto take = [&](size_t bytes) { char* r = p; p += (bytes + 255) & ~(size_t)255; return r; };
    float* dis     = (float*)take(sizeof(float) * n);
    float* g2      = (float*)take(sizeof(float) * n);
    __half* gh     = (__half*)take(sizeof(__half) * (size_t)n * H_DIM);
    int*   col     = (int*)take(sizeof(int) * (size_t)e);
    int*   packed  = (int*)take(sizeof(int) * (size_t)e);
    int*   rowp    = (int*)take(sizeof(int) * n);
    int*   rowe    = (int*)take(sizeof(int) * n);
    int*   cnt_mat = (int*)take(sizeof(int) * (size_t)NBLK1 * nb);
    int*   blk_base= (int*)take(sizeof(int) * (size_t)NBLK1 * nb);
    int*   tot     = (int*)take(sizeof(int) * nb);
    int*   starts  = (int*)take(sizeof(int) * (nb + 1));

    float* out = (float*)d_out;
    const int B = 256;

    k_count<<<NBLK1, T1, 0, stream>>>(dst, e, cnt_mat, nb);
    k_rowsum<<<nb, 64, 0, stream>>>(cnt_mat, tot, nb);
    k_scan2<<<1, 1024, 0, stream>>>(tot, starts, nb);
    k_bases2<<<NBLK1, T1, 0, stream>>>(cnt_mat, blk_base, e, nb);
    k_place<<<NBLK1, T1, 0, stream>>>(src, dst, e, blk_base, packed, nb);
    k_sort<<<nb, B, 0, stream>>>(packed, cnt_mat, blk_base, starts, col, rowp, rowe, dis, n, nb);
    k_gemm1<<<(n + B - 1) / B, B, 0, stream>>>(x, W1, dis, gh, n);
    k_p2n<<<(n + 63) / 64, B, 0, stream>>>(col, rowp, rowe, gh, dis, b1, W2, g2, n);
    k_p3n<<<(n + B - 1) / B, B, 0, stream>>>(col, rowp, rowe, g2, dis, b2, out, n);
}